// Round 11
// baseline (1425.856 us; speedup 1.0000x reference)
//
#include <hip/hip_runtime.h>

// CGLSTMEncoder via MFMA: 294912 seqs, T=120, H=32, D_IN=1.
// 16 seqs/wave, 8 mfma_f32_16x16x32_bf16 tiles/step (hi/lo bf16 split, 3
// MFMAs/tile => ~fp32). Transcendental-minimal elementwise (7 trans/elem).
// Round-16 change: CUT THE DS PIPE LOAD, KEEP 3 WAVES.
//   Evidence: r10 reached 3 waves/SIMD (occ 33.4%) with zero speedup --
//   but it paid +8 ds_read_b128/step for the reg diet. Per-CU DS pipe
//   accounting: r3 ~200 cyc/wave-step (~50% of wall), r10 ~300 (~75% --
//   the pipe the 3rd wave's capacity was spent on). Fix both sides:
//   * x-staging ELIMINATED: pre-kernel transposes x into ws [p][t][16s];
//     main kernel reads one 16B global load per quad per step (1 64B
//     line/wave-step, VMEM idle at HBM 1%), 1-step register prefetch.
//     Removes ~140 cyc/step DS (16 scattered b32 writes + 1 b128 read).
//   * reg diet via wx/bb->LDS (16 regs, 4 broadcast b128/step) instead of
//     blo (32 regs, 8 b128/step); blo back in registers. Demand ~160 <=
//     170 => 3 waves at the proven-safe (256,2) bound. Pooled-LDS alias
//     trick (r10-proven) keeps table loads in-loop.
//   * hb zero-init via b128.  Net DS ~120 cyc/step vs 200/300.
//   Fallback: ws_size checked; r10 kernel verbatim if too small.
//   Sentinels: WRITE_SIZE(main)=36864 KB; occupancy ~33%; VALUBusy 85+.
// Gate order i,f,g,o: o is dead code in the reference and skipped.
// Layouts (verified): A: m=lane&15,k=quad*8+j; B: n=lane&15 holds W rows;
// C/D: col=lane&15, row=quad*4+reg.

#define NV 9
#define TLEN 120
#define HS 32
#define BATCH_ 32768
#define NSEQ (BATCH_ * NV)
#define NBATCH (NSEQ / 16)   // 18432 batches of 16 seqs
#define WPB 4                // waves per block (independent batches)
#define GRID_ (NBATCH / WPB) // 4608 blocks, 1 batch per wave

#define HSTRIDE 36           // words per seq-row of hbuf
#define WBSTRIDE 20          // words per col-row of wb table

// pooled LDS layout (u32 words): hbuf[4][576] | wb[16][20]
#define HB_WORDS   (16 * HSTRIDE)            // 576 per wave
#define WB_OFF     (WPB * HB_WORDS)          // 2304
#define POOL_WORDS (WB_OFF + 16 * WBSTRIDE)  // 2624 words = 10496 B

#define LOG2E 1.4426950408889634f
#define TWOL  2.8853900817779268f

typedef __attribute__((ext_vector_type(8))) short bf16x8;
typedef __attribute__((ext_vector_type(4))) float f32x4;
typedef __attribute__((ext_vector_type(4))) unsigned int u32x4;

__device__ __forceinline__ float fast_exp2(float x) { return __builtin_amdgcn_exp2f(x); }
__device__ __forceinline__ float fast_rcp(float x)  { return __builtin_amdgcn_rcpf(x); }
__device__ __forceinline__ unsigned int fbits(float x) { return __builtin_bit_cast(unsigned int, x); }
__device__ __forceinline__ float bcastf(unsigned int x) { return __builtin_bit_cast(float, x); }

__device__ __forceinline__ f32x4 splat4(float x) { f32x4 v = {x, x, x, x}; return v; }
__device__ __forceinline__ f32x4 fma4(f32x4 a, f32x4 b, f32x4 c) {
  return __builtin_elementwise_fma(a, b, c);
}
__device__ __forceinline__ f32x4 exp24(f32x4 v) {
  f32x4 r;
  r[0] = fast_exp2(v[0]); r[1] = fast_exp2(v[1]);
  r[2] = fast_exp2(v[2]); r[3] = fast_exp2(v[3]);
  return r;
}
__device__ __forceinline__ f32x4 rcp4(f32x4 v) {
  f32x4 r;
  r[0] = fast_rcp(v[0]); r[1] = fast_rcp(v[1]);
  r[2] = fast_rcp(v[2]); r[3] = fast_rcp(v[3]);
  return r;
}

// merged-LSTM elementwise for 4 seqs: inputs are PRESCALED pre-activations
// (ai,af,ac by -log2e; ag by -2log2e); ct is the scaled cell state.
__device__ __forceinline__ void lstm_elem(f32x4 ai, f32x4 af, f32x4 ag, f32x4 ac,
                                          f32x4& ct, f32x4& h) {
  const f32x4 one4 = splat4(1.0f);
  f32x4 Ei = exp24(ai), Ef = exp24(af), Eg = exp24(ag), Ea = exp24(ac);
  f32x4 pi_ = Ei + one4, pf_ = Ef + one4, pg_ = Eg + one4, pa_ = Ea + one4;
  f32x4 u   = fma4(Eg, splat4(TWOL), splat4(-TWOL));   // (-2L)*(1-Eg)
  f32x4 P   = pi_ * pg_;
  f32x4 tt  = pf_ * u;
  f32x4 num = fma4(ct, P, tt);
  f32x4 den = pf_ * P;
  ct = num * rcp4(den);
  f32x4 Ec  = exp24(ct);
  h = (one4 - Ec) * rcp4(pa_ * (Ec + one4));
}

// ---------------- transpose pre-kernel: x[p-seqs][t] -> ws[p][t][16] ----
__global__ __launch_bounds__(256) void xpose_kernel(
    const float* __restrict__ x, float* __restrict__ xt) {
  const int p = blockIdx.x;
  __shared__ float tile[16 * TLEN];       // [s][t]
  const float4* xb = (const float4*)(x + (size_t)p * 16 * TLEN);
  float4* ob = (float4*)(xt + (size_t)p * 16 * TLEN);
  for (int i = threadIdx.x; i < 480; i += 256)
    ((float4*)tile)[i] = xb[i];           // contiguous copy into [s][t]
  __syncthreads();
  for (int i = threadIdx.x; i < 480; i += 256) {
    int o0 = i * 4;                       // linear out index = t*16 + s
    int t  = o0 >> 4;
    int e  = o0 & 15;                     // e in {0,4,8,12}
    float4 v;
    v.x = tile[(e + 0) * TLEN + t];
    v.y = tile[(e + 1) * TLEN + t];
    v.z = tile[(e + 2) * TLEN + t];
    v.w = tile[(e + 3) * TLEN + t];
    ob[i] = v;
  }
}

// ---------------- main kernel (transposed-x path) ----------------------
__global__ __launch_bounds__(256, 2) void cglstm_kernel(
    const float* __restrict__ xt_ws,  // [p][t][16]
    const float* __restrict__ W_ih,   // [128, 1]
    const float* __restrict__ W_hh,   // [128, 32]
    const float* __restrict__ b_ih,   // [128]
    const float* __restrict__ b_hh,   // [128]
    const float* __restrict__ cg_w,   // [32, 1]
    const float* __restrict__ cg_u,   // [32, 32]
    const float* __restrict__ cg_b,   // [32]
    float* __restrict__ out)          // flat [s*HS + j]
{
  const int lane = threadIdx.x & 63;
  const int wid  = threadIdx.x >> 6;
  const int col  = lane & 15;
  const int quad = lane >> 4;

  // ONE pooled LDS object: hbuf | wb table. Pack-stores may alias the wb
  // reads (same array), so the loop-invariant wb loads stay in-loop
  // instead of being hoisted into 16 registers (r10-proven trick).
  __shared__ __align__(16) unsigned int pool[POOL_WORDS];
  unsigned int* hb = &pool[wid * HB_WORDS];
  float* wbt = (float*)&pool[WB_OFF];     // [col][0..7]=wx, [8..15]=bb

  // ---- one-time: prescaled B fragments (W rows) as bf16 hi/lo ----
  bf16x8 bhi[8], blo[8];
#pragma unroll
  for (int tile = 0; tile < 8; ++tile) {
    const int n = col + (tile & 1) * 16;
    const float sc_ = ((tile >> 1) == 2) ? -TWOL : -LOG2E;  // g gate: -2L
    const float* wrow = (tile < 6) ? (W_hh + (size_t)((tile >> 1) * HS + n) * HS)
                                   : (cg_u + (size_t)n * HS);
    bf16x8 vh, vl;
#pragma unroll
    for (int e = 0; e < 8; ++e) {
      float wv = wrow[quad * 8 + e] * sc_;
      unsigned int wbits = fbits(wv);
      float lo_f = wv - bcastf(wbits & 0xffff0000u);
      vh[e] = (short)(wbits >> 16);
      vl[e] = (short)(fbits(lo_f) >> 16);
    }
    bhi[tile] = vh; blo[tile] = vl;
    // wx/bb -> LDS table (16 kernel-long regs saved); all waves write
    // identical values -> wave-internal ordering only, zero barriers
    float wxv, bbv;
    if (tile < 6) {
      const int gg = tile >> 1;
      wxv = W_ih[gg * HS + n] * sc_;
      bbv = (b_ih[gg * HS + n] + b_hh[gg * HS + n]) * sc_;
    } else {
      wxv = cg_w[n] * sc_;
      bbv = cg_b[n] * sc_;
    }
    if (quad == 0) {
      wbt[col * WBSTRIDE + tile]     = wxv;
      wbt[col * WBSTRIDE + 8 + tile] = bbv;
    }
  }

  const int p = blockIdx.x * WPB + wid;      // one 16-seq batch per wave
  const f32x4* xrow = (const f32x4*)(xt_ws + (size_t)p * 16 * TLEN); // [t*4+quad]

  for (int i = lane; i < HB_WORDS / 4; i += 64) ((u32x4*)hb)[i] = u32x4{0,0,0,0};
  f32x4 ct0 = splat4(0.f), ct1 = splat4(0.f), h0 = splat4(0.f), h1 = splat4(0.f);

  f32x4 xt_cur = xrow[quad];                 // t = 0 prefetched

#pragma unroll 1
  for (int t = 0; t < TLEN; ++t) {
    // prefetch next step's x (global, one 64B line per wave; VMEM pipe idle)
    int tn = (t < TLEN - 1) ? (t + 1) : t;
    f32x4 xt_nxt = xrow[tn * 4 + quad];
    // wx/bb from the pooled LDS table (broadcast within quad; 2-way banks)
    f32x4 wx03 = *(const f32x4*)&wbt[col * WBSTRIDE + 0];
    f32x4 wx47 = *(const f32x4*)&wbt[col * WBSTRIDE + 4];
    f32x4 bb03 = *(const f32x4*)&wbt[col * WBSTRIDE + 8];
    f32x4 bb47 = *(const f32x4*)&wbt[col * WBSTRIDE + 12];
    f32x4 acc[8];
#pragma unroll
    for (int k = 0; k < 4; ++k)
      acc[k] = fma4(splat4(wx03[k]), xt_cur, splat4(bb03[k]));
#pragma unroll
    for (int k = 0; k < 4; ++k)
      acc[4 + k] = fma4(splat4(wx47[k]), xt_cur, splat4(bb47[k]));
    // A fragments: h[m=col][k=quad*8..+7], hi/lo from packed words
    const unsigned int* hrow = &hb[col * HSTRIDE + quad * 8];
    u32x4 wa = *(const u32x4*)hrow;
    u32x4 wz = *(const u32x4*)(hrow + 4);
    u32x4 hi4, lo4;
    hi4[0] = __builtin_amdgcn_perm(wa[1], wa[0], 0x05040100u);
    hi4[1] = __builtin_amdgcn_perm(wa[3], wa[2], 0x05040100u);
    hi4[2] = __builtin_amdgcn_perm(wz[1], wz[0], 0x05040100u);
    hi4[3] = __builtin_amdgcn_perm(wz[3], wz[2], 0x05040100u);
    lo4[0] = __builtin_amdgcn_perm(wa[1], wa[0], 0x07060302u);
    lo4[1] = __builtin_amdgcn_perm(wa[3], wa[2], 0x07060302u);
    lo4[2] = __builtin_amdgcn_perm(wz[1], wz[0], 0x07060302u);
    lo4[3] = __builtin_amdgcn_perm(wz[3], wz[2], 0x07060302u);
    bf16x8 ahi = __builtin_bit_cast(bf16x8, hi4);
    bf16x8 alo = __builtin_bit_cast(bf16x8, lo4);
    // 3 passes of 8 independent MFMAs (bit-identical per-acc order)
#pragma unroll
    for (int k = 0; k < 8; ++k)
      acc[k] = __builtin_amdgcn_mfma_f32_16x16x32_bf16(ahi, bhi[k], acc[k], 0, 0, 0);
#pragma unroll
    for (int k = 0; k < 8; ++k)
      acc[k] = __builtin_amdgcn_mfma_f32_16x16x32_bf16(alo, bhi[k], acc[k], 0, 0, 0);
#pragma unroll
    for (int k = 0; k < 8; ++k)
      acc[k] = __builtin_amdgcn_mfma_f32_16x16x32_bf16(ahi, blo[k], acc[k], 0, 0, 0);
    // merged elementwise (7 trans/element), halves j=col and j=col+16
    lstm_elem(acc[0], acc[2], acc[4], acc[6], ct0, h0);
    lstm_elem(acc[1], acc[3], acc[5], acc[7], ct1, h1);
    // pack h -> (bf16hi | bf16lo) words for next step's A fragments
#pragma unroll
    for (int r = 0; r < 4; ++r) {
      unsigned int hbits = fbits(h0[r]);
      float lof = h0[r] - bcastf(hbits & 0xffff0000u);
      hb[(quad * 4 + r) * HSTRIDE + col] =
          __builtin_amdgcn_perm(fbits(lof), hbits, 0x07060302u);
      unsigned int hbits1 = fbits(h1[r]);
      float lof1 = h1[r] - bcastf(hbits1 & 0xffff0000u);
      hb[(quad * 4 + r) * HSTRIDE + col + 16] =
          __builtin_amdgcn_perm(fbits(lof1), hbits1, 0x07060302u);
    }
    xt_cur = xt_nxt;
    // no barrier: same-wave DS ordering guarantees h(t) visible at t+1
  }

  // ---- epilogue ----
  float* ob = out + (size_t)p * 16 * HS;
#pragma unroll
  for (int r = 0; r < 4; ++r) {
    ob[(quad * 4 + r) * HS + col]      = h0[r];
    ob[(quad * 4 + r) * HS + col + 16] = h1[r];
  }
}

// ---------------- fallback (r10 verbatim, ws-free) ---------------------
#define TCHUNK 60
#define XSTRIDE 20
#define FXT_WORDS   (TCHUNK * XSTRIDE)
#define FHB_OFF     (WPB * FXT_WORDS)
#define FBLO_OFF    (FHB_OFF + WPB * HB_WORDS)
#define FPOOL_WORDS (FBLO_OFF + 8 * 64 * 4)

__global__ __launch_bounds__(256, 2) void cglstm_kernel_fb(
    const float* __restrict__ x,
    const float* __restrict__ W_ih, const float* __restrict__ W_hh,
    const float* __restrict__ b_ih, const float* __restrict__ b_hh,
    const float* __restrict__ cg_w, const float* __restrict__ cg_u,
    const float* __restrict__ cg_b, float* __restrict__ out)
{
  const int lane = threadIdx.x & 63;
  const int wid  = threadIdx.x >> 6;
  const int col  = lane & 15;
  const int quad = lane >> 4;

  __shared__ __align__(16) unsigned int pool[FPOOL_WORDS];
  float* __restrict__ xTw = (float*)&pool[wid * FXT_WORDS];
  unsigned int* hb = &pool[FHB_OFF + wid * HB_WORDS];
  u32x4* blo_t = (u32x4*)&pool[FBLO_OFF];

  bf16x8 bhi[8];
  float wx[8], bb[8];
#pragma unroll
  for (int tile = 0; tile < 8; ++tile) {
    const int n = col + (tile & 1) * 16;
    const float sc_ = ((tile >> 1) == 2) ? -TWOL : -LOG2E;
    const float* wrow = (tile < 6) ? (W_hh + (size_t)((tile >> 1) * HS + n) * HS)
                                   : (cg_u + (size_t)n * HS);
    bf16x8 vh, vl;
#pragma unroll
    for (int e = 0; e < 8; ++e) {
      float wv = wrow[quad * 8 + e] * sc_;
      unsigned int wbits = fbits(wv);
      float lo_f = wv - bcastf(wbits & 0xffff0000u);
      vh[e] = (short)(wbits >> 16);
      vl[e] = (short)(fbits(lo_f) >> 16);
    }
    bhi[tile] = vh;
    blo_t[tile * 64 + lane] = __builtin_bit_cast(u32x4, vl);
    if (tile < 6) {
      const int gg = tile >> 1;
      wx[tile] = W_ih[gg * HS + n] * sc_;
      bb[tile] = (b_ih[gg * HS + n] + b_hh[gg * HS + n]) * sc_;
    } else {
      wx[tile] = cg_w[n] * sc_;
      bb[tile] = cg_b[n] * sc_;
    }
  }

  const int p = blockIdx.x * WPB + wid;
  const float4* xb = (const float4*)(x + (size_t)p * 16 * TLEN);

  for (int i = lane; i < 16 * HSTRIDE; i += 64) hb[i] = 0u;
  f32x4 ct0 = splat4(0.f), ct1 = splat4(0.f), h0 = splat4(0.f), h1 = splat4(0.f);

#pragma unroll 1
  for (int chunk = 0; chunk < 2; ++chunk) {
    for (int i = lane; i < 240; i += 64) {
      int s = i / 15;
      int j = i - s * 15;
      float4 v = xb[s * 30 + chunk * 15 + j];
      int t0 = j * 4;
      xTw[(t0 + 0) * XSTRIDE + s] = v.x;
      xTw[(t0 + 1) * XSTRIDE + s] = v.y;
      xTw[(t0 + 2) * XSTRIDE + s] = v.z;
      xTw[(t0 + 3) * XSTRIDE + s] = v.w;
    }
#pragma unroll 1
    for (int tl = 0; tl < TCHUNK; ++tl) {
      f32x4 xt4 = *(const f32x4*)&xTw[tl * XSTRIDE + quad * 4];
      f32x4 acc[8];
#pragma unroll
      for (int tile = 0; tile < 8; ++tile)
        acc[tile] = fma4(splat4(wx[tile]), xt4, splat4(bb[tile]));
      const unsigned int* hrow = &hb[col * HSTRIDE + quad * 8];
      u32x4 wa = *(const u32x4*)hrow;
      u32x4 wz = *(const u32x4*)(hrow + 4);
      u32x4 hi4, lo4;
      hi4[0] = __builtin_amdgcn_perm(wa[1], wa[0], 0x05040100u);
      hi4[1] = __builtin_amdgcn_perm(wa[3], wa[2], 0x05040100u);
      hi4[2] = __builtin_amdgcn_perm(wz[1], wz[0], 0x05040100u);
      hi4[3] = __builtin_amdgcn_perm(wz[3], wz[2], 0x05040100u);
      lo4[0] = __builtin_amdgcn_perm(wa[1], wa[0], 0x07060302u);
      lo4[1] = __builtin_amdgcn_perm(wa[3], wa[2], 0x07060302u);
      lo4[2] = __builtin_amdgcn_perm(wz[1], wz[0], 0x07060302u);
      lo4[3] = __builtin_amdgcn_perm(wz[3], wz[2], 0x07060302u);
      bf16x8 ahi = __builtin_bit_cast(bf16x8, hi4);
      bf16x8 alo = __builtin_bit_cast(bf16x8, lo4);
#pragma unroll
      for (int tile = 0; tile < 8; ++tile) {
        bf16x8 blo_c = __builtin_bit_cast(bf16x8, blo_t[tile * 64 + lane]);
        acc[tile] = __builtin_amdgcn_mfma_f32_16x16x32_bf16(ahi, bhi[tile], acc[tile], 0, 0, 0);
        acc[tile] = __builtin_amdgcn_mfma_f32_16x16x32_bf16(alo, bhi[tile], acc[tile], 0, 0, 0);
        acc[tile] = __builtin_amdgcn_mfma_f32_16x16x32_bf16(ahi, blo_c, acc[tile], 0, 0, 0);
      }
      lstm_elem(acc[0], acc[2], acc[4], acc[6], ct0, h0);
      lstm_elem(acc[1], acc[3], acc[5], acc[7], ct1, h1);
#pragma unroll
      for (int r = 0; r < 4; ++r) {
        unsigned int hbits = fbits(h0[r]);
        float lof = h0[r] - bcastf(hbits & 0xffff0000u);
        hb[(quad * 4 + r) * HSTRIDE + col] =
            __builtin_amdgcn_perm(fbits(lof), hbits, 0x07060302u);
        unsigned int hbits1 = fbits(h1[r]);
        float lof1 = h1[r] - bcastf(hbits1 & 0xffff0000u);
        hb[(quad * 4 + r) * HSTRIDE + col + 16] =
            __builtin_amdgcn_perm(fbits(lof1), hbits1, 0x07060302u);
      }
    }
  }

  float* ob = out + (size_t)p * 16 * HS;
#pragma unroll
  for (int r = 0; r < 4; ++r) {
    ob[(quad * 4 + r) * HS + col]      = h0[r];
    ob[(quad * 4 + r) * HS + col + 16] = h1[r];
  }
}

extern "C" void kernel_launch(void* const* d_in, const int* in_sizes, int n_in,
                              void* d_out, int out_size, void* d_ws, size_t ws_size,
                              hipStream_t stream) {
  const float* x    = (const float*)d_in[0];
  const float* W_ih = (const float*)d_in[1];
  const float* W_hh = (const float*)d_in[2];
  const float* b_ih = (const float*)d_in[3];
  const float* b_hh = (const float*)d_in[4];
  const float* cg_w = (const float*)d_in[5];
  const float* cg_u = (const float*)d_in[6];
  const float* cg_b = (const float*)d_in[7];
  float* out = (float*)d_out;

  const size_t ws_need = (size_t)NBATCH * 16 * TLEN * sizeof(float); // 141.6 MB
  if (d_ws != nullptr && ws_size >= ws_need) {
    float* xt = (float*)d_ws;
    hipLaunchKernelGGL(xpose_kernel, dim3(NBATCH), dim3(256), 0, stream, x, xt);
    hipLaunchKernelGGL(cglstm_kernel, dim3(GRID_), dim3(256), 0, stream,
                       xt, W_ih, W_hh, b_ih, b_hh, cg_w, cg_u, cg_b, out);
  } else {
    hipLaunchKernelGGL(cglstm_kernel_fb, dim3(GRID_), dim3(256), 0, stream,
                       x, W_ih, W_hh, b_ih, b_hh, cg_w, cg_u, cg_b, out);
  }
}